// Round 5
// baseline (218.171 us; speedup 1.0000x reference)
//
#include <hip/hip_runtime.h>

#define HS   512
#define WSZ  512
#define NC   64
#define HW   (HS * WSZ)
#define KCAP 16       // inverted-map bin capacity (Poisson(1)/bin; P(>16) ~ 1e-14)
#define LCAP 32       // per-target LDS list capacity (Poisson(9); P(>32) ~ 3e-5 overall)
#define SENT 0x40000  // sentinel q -> zeroed pixel record appended at refu4[HW]

typedef unsigned int uint;
typedef unsigned short ushort;

// float -> bf16 (round-to-nearest-even), raw bits
__device__ __forceinline__ ushort f2bf(float f) {
    uint b = __float_as_uint(f);
    return (ushort)((b + 0x7FFFu + ((b >> 16) & 1u)) >> 16);
}

// ---------------------------------------------------------------------------
// FUSED prep + fill (unchanged from R4 — passing).  Blocks [0,4096):
// transpose ref (C,H,W) f32 -> refu4 (H*W+1, 8) uint4 (packed bf16 pairs,
// 128B/pixel).  Blocks [4096,5120): invert nnf_rs into bins (1 atomic/pixel).
// Block 4096 zeroes the sentinel record refu4[HW].  cnt zeroed by
// hipMemsetAsync before this kernel.
// ---------------------------------------------------------------------------
__global__ __launch_bounds__(256) void prep_fill(
    const float4* __restrict__ ref4, uint4* __restrict__ refu4,
    const int2* __restrict__ nnf_rs, int* __restrict__ cnt,
    int* __restrict__ slots)
{
    __shared__ float lds[64 * 65];
    const int tid = threadIdx.x;

    if (blockIdx.x < 4096) {
        const int p0 = blockIdx.x * 64;        // 64 pixels / tile
#pragma unroll
        for (int k = 0; k < 4; ++k) {
            int e  = k * 256 + tid;            // 1024 float4 per tile
            int c  = e >> 4;                   // channel
            int i4 = e & 15;                   // pixel quad
            float4 v = ref4[(size_t)c * (HW / 4) + (p0 >> 2) + i4];
            lds[(i4 * 4 + 0) * 65 + c] = v.x;
            lds[(i4 * 4 + 1) * 65 + c] = v.y;
            lds[(i4 * 4 + 2) * 65 + c] = v.z;
            lds[(i4 * 4 + 3) * 65 + c] = v.w;
        }
        __syncthreads();
#pragma unroll
        for (int k = 0; k < 2; ++k) {
            int e = k * 256 + tid;             // 512 uint4 per tile
            int i = e >> 3;                    // pixel
            int q = e & 7;                     // channel octet
            const float* row = &lds[i * 65 + 8 * q];
            uint4 u;
            u.x = (uint)f2bf(row[0]) | ((uint)f2bf(row[1]) << 16);
            u.y = (uint)f2bf(row[2]) | ((uint)f2bf(row[3]) << 16);
            u.z = (uint)f2bf(row[4]) | ((uint)f2bf(row[5]) << 16);
            u.w = (uint)f2bf(row[6]) | ((uint)f2bf(row[7]) << 16);
            refu4[(size_t)(p0 + i) * 8 + q] = u;
        }
    } else {
        if (blockIdx.x == 4096 && tid < 8) {   // zero the sentinel record
            uint4 z; z.x = 0u; z.y = 0u; z.z = 0u; z.w = 0u;
            refu4[(size_t)HW * 8 + tid] = z;
        }
        const int r = (blockIdx.x - 4096) * 256 + tid;
        const int2 s = nnf_rs[r];              // (sy, sx), values in [0,512)
        const int bin = (s.x << 9) | s.y;
        const int pos = atomicAdd(&cnt[bin], 1);
        if (pos < KCAP) slots[(bin << 4) + pos] = r;
    }
}

// ---------------------------------------------------------------------------
// gather_lds: 32 targets/block, 8 lanes/target over channel octets.
// Phase E expands the 9-tap inverted contributions into per-target LDS lists
// (pre-offset, pre-validated; R3-proven).  NEW vs R4 — memory-level
// parallelism: R4's ACCUM macro produced load->waitcnt->unpack serial chains
// (VGPR=40, ~2 loads in flight, 65% latency stall at ~900cy HBM-miss).
// Now pass 1 computes all 9 indices first, issues all 9 record loads as a
// burst (~36 VGPRs of results in flight), then unpacks; pass 2 loads its 4
// records + prefetches the next LDS quad before unpacking.  All names are
// static scalars (no runtime-indexed arrays -> no scratch).
// ---------------------------------------------------------------------------
__global__ __launch_bounds__(256) void gather_lds(
    const uint4* __restrict__ refu4,
    const int2*  __restrict__ nnf_sr,
    const int*   __restrict__ cnt,
    const int*   __restrict__ slots,
    float* __restrict__ out)
{
    const float ws = 1.0f / 262144.0f;   // 2^-18 exact
    const float wr = 2.0f / 262144.0f;   // 2^-17 exact

    __shared__ __align__(16) int lists[32][36];  // 36-int rows: 16B-aligned,
                                                 // prefetch at s+4<=32 stays in-row
    __shared__ int  lcnt[32];
    __shared__ int  bcnt[102];           // 3 rows x 34 cols of neighbor bins
    __shared__ int2 snn[102];            // nnf_sr staged for the same bins

    const int tid = threadIdx.x;
    const int t0  = blockIdx.x * 32;     // 32 targets, all in row ty0
    const int ty0 = t0 >> 9, tx0 = t0 & 511;

    // ---- phase E0: stage bin counts + nnf_sr, SENT-fill lists ----
    if (tid < 32) lcnt[tid] = 0;
    if (tid < 102) {
        const int jr = tid / 34, jc = tid - jr * 34;
        const int sy = ty0 + jr - 1, sx = tx0 + jc - 1;
        const bool sv = ((unsigned)sy < 512u) & ((unsigned)sx < 512u);
        const int sidx = ((sy & 511) << 9) | (sx & 511);   // clamped-in-range
        bcnt[tid] = sv ? min(cnt[sidx], KCAP) : 0;
        snn[tid]  = nnf_sr[sidx];        // garbage ok when !sv (masked later)
    }
    {
        int4 s4; s4.x = SENT; s4.y = SENT; s4.z = SENT; s4.w = SENT;
        for (int p = tid; p < 288; p += 256)       // 32*36 ints = 288 int4
            ((int4*)lists)[p] = s4;
    }
    __syncthreads();

    // ---- phase E1: expand 102 bins x 3 dx-taps into per-target lists ----
    for (int p = tid; p < 306; p += 256) {
        const int j  = p / 3;
        const int di = p - j * 3;              // dx = di-1
        const int jr = j / 34, jc = j - jr * 34;
        const int dy = 1 - jr;                 // unique dy for this bin row
        const int dx = di - 1;
        const int lt = jc - 1 + dx;            // local target index
        const int c  = bcnt[j];
        if (((unsigned)lt < 32u) && (c > 0)) {
            const int sy = ty0 + jr - 1, sx = tx0 + jc - 1;
            const int sbase = (((sy << 9) | sx) << 4);
            for (int e = 0; e < c; ++e) {
                const int r  = slots[sbase + e];
                const int qy = (r >> 9) + dy, qx = (r & 511) + dx;
                if (((unsigned)qy < 512u) & ((unsigned)qx < 512u)) {
                    const int pos = atomicAdd(&lcnt[lt], 1);
                    if (pos < LCAP) lists[lt][pos] = (qy << 9) | qx;
                }
            }
        }
    }
    __syncthreads();

    // ---- per-thread identity ----
    const int k  = tid & 7;                    // channel octet
    const int lt = tid >> 3;                   // local target
    const uint4* __restrict__ refk = refu4 + k;

    float a0=0,a1=0,a2=0,a3=0,a4=0,a5=0,a6=0,a7=0;
    int nv = 0;

    // ---- pass 1 index calc: all 9 tap indices, no loads yet ----
#define TAPQ(i, dy, dx)                                                       \
    int q##i; {                                                               \
        const bool rv = ((unsigned)(ty0 - (dy)) < 512u);      /* uniform */   \
        const bool cv = ((unsigned)(tx0 + lt - (dx)) < 512u);                 \
        const int2 nn = snn[(1 - (dy)) * 34 + (lt - (dx) + 1)];               \
        const int qy = nn.x + (dy), qx = nn.y + (dx);                         \
        const bool v = rv & cv &                                              \
                       ((unsigned)qy < 512u) & ((unsigned)qx < 512u);         \
        q##i = v ? ((qy << 9) | qx) : SENT;                                   \
        nv += v ? 1 : 0;                                                      \
    }

    TAPQ(0, -1, -1)  TAPQ(1, -1, 0)  TAPQ(2, -1, 1)
    TAPQ(3,  0, -1)  TAPQ(4,  0, 0)  TAPQ(5,  0, 1)
    TAPQ(6,  1, -1)  TAPQ(7,  1, 0)  TAPQ(8,  1, 1)
#undef TAPQ

    // ---- pass 1 load burst: 9 independent record reads in flight ----
    const uint4 u0 = refk[(size_t)q0 * 8];
    const uint4 u1 = refk[(size_t)q1 * 8];
    const uint4 u2 = refk[(size_t)q2 * 8];
    const uint4 u3 = refk[(size_t)q3 * 8];
    const uint4 u4 = refk[(size_t)q4 * 8];
    const uint4 u5 = refk[(size_t)q5 * 8];
    const uint4 u6 = refk[(size_t)q6 * 8];
    const uint4 u7 = refk[(size_t)q7 * 8];
    const uint4 u8 = refk[(size_t)q8 * 8];

    // prefetch first pass-2 quad while pass-1 loads are in flight
    int4 e = *(const int4*)&lists[lt][0];
    const int Sreal = min(lcnt[lt], LCAP);
    const int S4 = (Sreal + 3) & ~3;

#define UNPACK(u_)                                                            \
    {                                                                         \
        a0 += __uint_as_float(u_.x << 16);                                    \
        a1 += __uint_as_float(u_.x & 0xffff0000u);                            \
        a2 += __uint_as_float(u_.y << 16);                                    \
        a3 += __uint_as_float(u_.y & 0xffff0000u);                            \
        a4 += __uint_as_float(u_.z << 16);                                    \
        a5 += __uint_as_float(u_.z & 0xffff0000u);                            \
        a6 += __uint_as_float(u_.w << 16);                                    \
        a7 += __uint_as_float(u_.w & 0xffff0000u);                            \
    }

    UNPACK(u0) UNPACK(u1) UNPACK(u2) UNPACK(u3) UNPACK(u4)
    UNPACK(u5) UNPACK(u6) UNPACK(u7) UNPACK(u8)

    // fold pass-1 into pass-2 scale domain: ws = 0.5*wr (exact pow2 scale)
    a0 *= 0.5f; a1 *= 0.5f; a2 *= 0.5f; a3 *= 0.5f;
    a4 *= 0.5f; a5 *= 0.5f; a6 *= 0.5f; a7 *= 0.5f;

    // ---- pass 2: software-pipelined maskless walk (tails are SENT=zero) ---
    for (int s = 0; s < S4; s += 4) {
        const uint4 v0 = refk[(size_t)(e.x) * 8];
        const uint4 v1 = refk[(size_t)(e.y) * 8];
        const uint4 v2 = refk[(size_t)(e.z) * 8];
        const uint4 v3 = refk[(size_t)(e.w) * 8];
        const int4 en = *(const int4*)&lists[lt][s + 4];  // in-row (s+4<=32<36)
        UNPACK(v0) UNPACK(v1) UNPACK(v2) UNPACK(v3)
        e = en;
    }
#undef UNPACK

    // ---- epilogue: w = ws*nv + wr*Sreal (exact); out = a * wr / w ----
    const float wsum = ws * (float)nv + wr * (float)Sreal;   // nv>=1 always
    const float sc = wr / wsum;
    const int t = t0 + lt;
    size_t o = (size_t)(8 * k) * HW + t;
    out[o]                = a0 * sc;
    out[o + 1*(size_t)HW] = a1 * sc;
    out[o + 2*(size_t)HW] = a2 * sc;
    out[o + 3*(size_t)HW] = a3 * sc;
    out[o + 4*(size_t)HW] = a4 * sc;
    out[o + 5*(size_t)HW] = a5 * sc;
    out[o + 6*(size_t)HW] = a6 * sc;
    out[o + 7*(size_t)HW] = a7 * sc;
}

// ===========================================================================
// Fallback (tiny workspace): bins only, gather channel-major f32 ref with
// the SEL-chain walk.  Unchanged from baseline.
// ===========================================================================
__global__ __launch_bounds__(256) void fill_bins(
    const int2* __restrict__ nnf_rs, int* __restrict__ cnt,
    int* __restrict__ slots)
{
    int r = blockIdx.x * 256 + threadIdx.x;
    int2 s = nnf_rs[r];
    int bin = (s.x << 9) | s.y;
    int pos = atomicAdd(&cnt[bin], 1);
    if (pos < KCAP) slots[(bin << 4) + pos] = r;
}

__global__ __launch_bounds__(256) void gather8_f32(
    const float* __restrict__ reff,
    const int2*  __restrict__ nnf_sr,
    const int*   __restrict__ cnt,
    const int*   __restrict__ slots,
    float* __restrict__ out)
{
    const float ws = 1.0f / 262144.0f;
    const float wr = 2.0f / 262144.0f;

    const int tid = threadIdx.x;
    const int k   = tid & 7;
    const int t   = blockIdx.x * 32 + (tid >> 3);
    const int ty  = t >> 9, tx = t & 511;

    float a0=0,a1=0,a2=0,a3=0,a4=0,a5=0,a6=0,a7=0, w=0.f;

#define ACCUM(qv, mv)                                                         \
    {                                                                         \
        const int   q_ = (qv);                                                \
        const float m_ = (mv);                                                \
        const size_t c0_ = (size_t)(8 * k) * HW + q_;                         \
        a0 += reff[c0_ + 0*(size_t)HW] * m_;                                  \
        a1 += reff[c0_ + 1*(size_t)HW] * m_;                                  \
        a2 += reff[c0_ + 2*(size_t)HW] * m_;                                  \
        a3 += reff[c0_ + 3*(size_t)HW] * m_;                                  \
        a4 += reff[c0_ + 4*(size_t)HW] * m_;                                  \
        a5 += reff[c0_ + 5*(size_t)HW] * m_;                                  \
        a6 += reff[c0_ + 6*(size_t)HW] * m_;                                  \
        a7 += reff[c0_ + 7*(size_t)HW] * m_;                                  \
        w += m_;                                                              \
    }

    int mt0,mt1,mt2,mt3,mt4,mt5,mt6,mt7,mt8;
    int run = 0;

#define TAP(i, dy, dx)                                                        \
    {                                                                         \
        const int sy = ty - (dy), sx = tx - (dx);                             \
        const bool sval = ((unsigned)sy < 512u) & ((unsigned)sx < 512u);      \
        const int sidx = ((sy & 511) << 9) | (sx & 511);                      \
        mt##i = (sidx << 12) | ((i) << 8) | run;                              \
        const int c = cnt[sidx];                                              \
        run += sval ? min(c, KCAP) : 0;                                       \
        const int2 nn = nnf_sr[sidx];                                         \
        const int qy = nn.x + (dy), qx = nn.y + (dx);                         \
        const bool v = sval & ((unsigned)qy < 512u) & ((unsigned)qx < 512u);  \
        ACCUM((((qy & 511) << 9) | (qx & 511)), v ? ws : 0.f)                 \
    }

    TAP(0, -1, -1)  TAP(1, -1, 0)  TAP(2, -1, 1)
    TAP(3,  0, -1)  TAP(4,  0, 0)  TAP(5,  0, 1)
    TAP(6,  1, -1)  TAP(7,  1, 0)  TAP(8,  1, 1)
#undef TAP

    const int S = run;

#define SEL(i)  m_ = (s_ >= (mt##i & 255)) ? mt##i : m_;
#define ENTRY(sv)                                                             \
    {                                                                         \
        const int s_ = (sv);                                                  \
        int m_ = mt0;                                                         \
        SEL(1) SEL(2) SEL(3) SEL(4) SEL(5) SEL(6) SEL(7) SEL(8)               \
        const int off_ = m_ & 255;                                            \
        const int ii_  = (m_ >> 8) & 15;                                      \
        const int bs_  = (m_ >> 12) << 4;                                     \
        const int idx_ = min(s_ - off_, KCAP - 1);                            \
        const int e_   = slots[bs_ + idx_];                                   \
        const int ry_  = (e_ >> 9) & 511, rx_ = e_ & 511;                     \
        const int dyp_ = (ii_ * 11) >> 5;                                     \
        const int dy_  = dyp_ - 1, dx_ = ii_ - 3 * dyp_ - 1;                  \
        const int qy_  = ry_ + dy_, qx_ = rx_ + dx_;                          \
        const bool v_  = (s_ < S) &                                           \
                         ((unsigned)qy_ < 512u) & ((unsigned)qx_ < 512u);     \
        ACCUM((((qy_ & 511) << 9) | (qx_ & 511)), v_ ? wr : 0.f)              \
    }

    for (int s = 0; s < S; s += 2) {
        ENTRY(s)
        ENTRY(s + 1)
    }
#undef ENTRY
#undef SEL
#undef ACCUM

    if (w == 0.f) w = 1.f;
    const float inv = 1.f / w;
    size_t o = (size_t)(8 * k) * HW + t;
    out[o]                = a0 * inv;
    out[o + 1*(size_t)HW] = a1 * inv;
    out[o + 2*(size_t)HW] = a2 * inv;
    out[o + 3*(size_t)HW] = a3 * inv;
    out[o + 4*(size_t)HW] = a4 * inv;
    out[o + 5*(size_t)HW] = a5 * inv;
    out[o + 6*(size_t)HW] = a6 * inv;
    out[o + 7*(size_t)HW] = a7 * inv;
}

extern "C" void kernel_launch(void* const* d_in, const int* in_sizes, int n_in,
                              void* d_out, int out_size, void* d_ws, size_t ws_size,
                              hipStream_t stream)
{
    const float* ref    = (const float*)d_in[0];
    const int2*  nnf_sr = (const int2*)d_in[1];
    const int2*  nnf_rs = (const int2*)d_in[2];
    float* out = (float*)d_out;

    char* wsb = (char*)d_ws;
    const size_t refT_bytes = (size_t)HW * NC * 2 + 128;  // +128B sentinel rec
    const size_t cnt_bytes  = (size_t)HW * 4;             //  1 MiB
    const size_t slot_bytes = (size_t)HW * KCAP * 4;      // 16 MiB

    if (ws_size >= refT_bytes + cnt_bytes + slot_bytes) {   // ~49 MiB
        uint4* refu4 = (uint4*)wsb;
        int*   cntp  = (int*)(wsb + refT_bytes);
        int*   slots = (int*)(wsb + refT_bytes + cnt_bytes);

        hipMemsetAsync(cntp, 0, cnt_bytes, stream);
        prep_fill<<<4096 + HW / 256, 256, 0, stream>>>(
            (const float4*)ref, refu4, nnf_rs, cntp, slots);
        gather_lds<<<HW / 32, 256, 0, stream>>>(refu4, nnf_sr, cntp, slots, out);
    } else {
        // fallback: bins only, gather channel-major f32 ref directly
        int* cntp  = (int*)wsb;
        int* slots = cntp + HW;
        hipMemsetAsync(cntp, 0, cnt_bytes, stream);
        fill_bins<<<HW / 256, 256, 0, stream>>>(nnf_rs, cntp, slots);
        gather8_f32<<<HW / 32, 256, 0, stream>>>(ref, nnf_sr, cntp, slots, out);
    }
}

// Round 6
// 217.368 us; speedup vs baseline: 1.0037x; 1.0037x over previous
//
#include <hip/hip_runtime.h>

#define HS   512
#define WSZ  512
#define NC   64
#define HW   (HS * WSZ)
#define KCAP 16       // inverted-map bin capacity (Poisson(1)/bin; P(>16) ~ 1e-14)
#define LCAP 32       // per-target LDS list capacity (Poisson(9); P(>32) ~ 3e-5 overall)
#define LROW 40       // list row stride (ints): 32 entries + 8 pad so the
                      // 8-deep pipeline's LDS prefetch (max idx 39) stays in-row
#define SENT 0x40000  // sentinel q -> zeroed pixel record appended at refu4[HW]

typedef unsigned int uint;
typedef unsigned short ushort;

// float -> bf16 (round-to-nearest-even), raw bits
__device__ __forceinline__ ushort f2bf(float f) {
    uint b = __float_as_uint(f);
    return (ushort)((b + 0x7FFFu + ((b >> 16) & 1u)) >> 16);
}

// ---------------------------------------------------------------------------
// FUSED prep + fill (unchanged — passing since R4).  Blocks [0,4096):
// transpose ref (C,H,W) f32 -> refu4 (H*W+1, 8) uint4 (packed bf16 pairs,
// 128B/pixel).  Blocks [4096,5120): invert nnf_rs into bins (1 atomic/pixel).
// Block 4096 zeroes the sentinel record refu4[HW].  cnt zeroed by
// hipMemsetAsync before this kernel.
// ---------------------------------------------------------------------------
__global__ __launch_bounds__(256) void prep_fill(
    const float4* __restrict__ ref4, uint4* __restrict__ refu4,
    const int2* __restrict__ nnf_rs, int* __restrict__ cnt,
    int* __restrict__ slots)
{
    __shared__ float lds[64 * 65];
    const int tid = threadIdx.x;

    if (blockIdx.x < 4096) {
        const int p0 = blockIdx.x * 64;        // 64 pixels / tile
#pragma unroll
        for (int k = 0; k < 4; ++k) {
            int e  = k * 256 + tid;            // 1024 float4 per tile
            int c  = e >> 4;                   // channel
            int i4 = e & 15;                   // pixel quad
            float4 v = ref4[(size_t)c * (HW / 4) + (p0 >> 2) + i4];
            lds[(i4 * 4 + 0) * 65 + c] = v.x;
            lds[(i4 * 4 + 1) * 65 + c] = v.y;
            lds[(i4 * 4 + 2) * 65 + c] = v.z;
            lds[(i4 * 4 + 3) * 65 + c] = v.w;
        }
        __syncthreads();
#pragma unroll
        for (int k = 0; k < 2; ++k) {
            int e = k * 256 + tid;             // 512 uint4 per tile
            int i = e >> 3;                    // pixel
            int q = e & 7;                     // channel octet
            const float* row = &lds[i * 65 + 8 * q];
            uint4 u;
            u.x = (uint)f2bf(row[0]) | ((uint)f2bf(row[1]) << 16);
            u.y = (uint)f2bf(row[2]) | ((uint)f2bf(row[3]) << 16);
            u.z = (uint)f2bf(row[4]) | ((uint)f2bf(row[5]) << 16);
            u.w = (uint)f2bf(row[6]) | ((uint)f2bf(row[7]) << 16);
            refu4[(size_t)(p0 + i) * 8 + q] = u;
        }
    } else {
        if (blockIdx.x == 4096 && tid < 8) {   // zero the sentinel record
            uint4 z; z.x = 0u; z.y = 0u; z.z = 0u; z.w = 0u;
            refu4[(size_t)HW * 8 + tid] = z;
        }
        const int r = (blockIdx.x - 4096) * 256 + tid;
        const int2 s = nnf_rs[r];              // (sy, sx), values in [0,512)
        const int bin = (s.x << 9) | s.y;
        const int pos = atomicAdd(&cnt[bin], 1);
        if (pos < KCAP) slots[(bin << 4) + pos] = r;
    }
}

// ---------------------------------------------------------------------------
// gather_lds: 32 targets/block, 8 lanes/target over channel octets.
// Phase E (R3-proven) expands inverted contributions into per-target LDS
// lists.  NEW vs R5: the load bursts are fenced with sched_barrier(0) so the
// register allocator CANNOT re-serialize them (R4/R5 both compiled to
// VGPR=40 => only ~4 loads in flight; BDP says ~9 KB/CU in flight is needed
// for ~6 TB/s, we had ~9 KB borderline).  Pass 1: 9 record loads issued,
// fence, then unpack.  Pass 2: 8 records/iter + dual int4 LDS prefetch,
// fence, unpack.  Accumulation order per accumulator is unchanged =>
// bitwise-identical output to R4/R5.
// ---------------------------------------------------------------------------
__global__ __launch_bounds__(256) void gather_lds(
    const uint4* __restrict__ refu4,
    const int2*  __restrict__ nnf_sr,
    const int*   __restrict__ cnt,
    const int*   __restrict__ slots,
    float* __restrict__ out)
{
    const float ws = 1.0f / 262144.0f;   // 2^-18 exact
    const float wr = 2.0f / 262144.0f;   // 2^-17 exact

    __shared__ __align__(16) int lists[32][LROW];
    __shared__ int  lcnt[32];
    __shared__ int  bcnt[102];           // 3 rows x 34 cols of neighbor bins
    __shared__ int2 snn[102];            // nnf_sr staged for the same bins

    const int tid = threadIdx.x;
    const int t0  = blockIdx.x * 32;     // 32 targets, all in row ty0
    const int ty0 = t0 >> 9, tx0 = t0 & 511;

    // ---- phase E0: stage bin counts + nnf_sr, SENT-fill lists ----
    if (tid < 32) lcnt[tid] = 0;
    if (tid < 102) {
        const int jr = tid / 34, jc = tid - jr * 34;
        const int sy = ty0 + jr - 1, sx = tx0 + jc - 1;
        const bool sv = ((unsigned)sy < 512u) & ((unsigned)sx < 512u);
        const int sidx = ((sy & 511) << 9) | (sx & 511);   // clamped-in-range
        bcnt[tid] = sv ? min(cnt[sidx], KCAP) : 0;
        snn[tid]  = nnf_sr[sidx];        // garbage ok when !sv (masked later)
    }
    {
        int4 s4; s4.x = SENT; s4.y = SENT; s4.z = SENT; s4.w = SENT;
        for (int p = tid; p < 32 * LROW / 4; p += 256)     // 320 int4
            ((int4*)lists)[p] = s4;
    }
    __syncthreads();

    // ---- phase E1: expand 102 bins x 3 dx-taps into per-target lists ----
    for (int p = tid; p < 306; p += 256) {
        const int j  = p / 3;
        const int di = p - j * 3;              // dx = di-1
        const int jr = j / 34, jc = j - jr * 34;
        const int dy = 1 - jr;                 // unique dy for this bin row
        const int dx = di - 1;
        const int lt = jc - 1 + dx;            // local target index
        const int c  = bcnt[j];
        if (((unsigned)lt < 32u) && (c > 0)) {
            const int sy = ty0 + jr - 1, sx = tx0 + jc - 1;
            const int sbase = (((sy << 9) | sx) << 4);
            for (int e = 0; e < c; ++e) {
                const int r  = slots[sbase + e];
                const int qy = (r >> 9) + dy, qx = (r & 511) + dx;
                if (((unsigned)qy < 512u) & ((unsigned)qx < 512u)) {
                    const int pos = atomicAdd(&lcnt[lt], 1);
                    if (pos < LCAP) lists[lt][pos] = (qy << 9) | qx;
                }
            }
        }
    }
    __syncthreads();

    // ---- per-thread identity ----
    const int k  = tid & 7;                    // channel octet
    const int lt = tid >> 3;                   // local target
    const uint4* __restrict__ refk = refu4 + k;

    float a0=0,a1=0,a2=0,a3=0,a4=0,a5=0,a6=0,a7=0;
    int nv = 0;

    // ---- pass 1 index calc: all 9 tap indices, no loads yet ----
#define TAPQ(i, dy, dx)                                                       \
    int q##i; {                                                               \
        const bool rv = ((unsigned)(ty0 - (dy)) < 512u);      /* uniform */   \
        const bool cv = ((unsigned)(tx0 + lt - (dx)) < 512u);                 \
        const int2 nn = snn[(1 - (dy)) * 34 + (lt - (dx) + 1)];               \
        const int qy = nn.x + (dy), qx = nn.y + (dx);                         \
        const bool v = rv & cv &                                              \
                       ((unsigned)qy < 512u) & ((unsigned)qx < 512u);         \
        q##i = v ? ((qy << 9) | qx) : SENT;                                   \
        nv += v ? 1 : 0;                                                      \
    }

    TAPQ(0, -1, -1)  TAPQ(1, -1, 0)  TAPQ(2, -1, 1)
    TAPQ(3,  0, -1)  TAPQ(4,  0, 0)  TAPQ(5,  0, 1)
    TAPQ(6,  1, -1)  TAPQ(7,  1, 0)  TAPQ(8,  1, 1)
#undef TAPQ

    // ---- pass 1 load burst: 9 record reads, FENCED so all stay in flight --
    const uint4 u0 = refk[(size_t)q0 * 8];
    const uint4 u1 = refk[(size_t)q1 * 8];
    const uint4 u2 = refk[(size_t)q2 * 8];
    const uint4 u3 = refk[(size_t)q3 * 8];
    const uint4 u4 = refk[(size_t)q4 * 8];
    const uint4 u5 = refk[(size_t)q5 * 8];
    const uint4 u6 = refk[(size_t)q6 * 8];
    const uint4 u7 = refk[(size_t)q7 * 8];
    const uint4 u8 = refk[(size_t)q8 * 8];

    // overlap LDS prefetch of the first pass-2 quads with the global burst
    int4 e = *(const int4*)&lists[lt][0];
    int4 f = *(const int4*)&lists[lt][4];
    const int Sreal = min(lcnt[lt], LCAP);
    const int S8 = (Sreal + 7) & ~7;

    __builtin_amdgcn_sched_barrier(0);   // nothing crosses: loads all issued

#define UNPACK(u_)                                                            \
    {                                                                         \
        a0 += __uint_as_float(u_.x << 16);                                    \
        a1 += __uint_as_float(u_.x & 0xffff0000u);                            \
        a2 += __uint_as_float(u_.y << 16);                                    \
        a3 += __uint_as_float(u_.y & 0xffff0000u);                            \
        a4 += __uint_as_float(u_.z << 16);                                    \
        a5 += __uint_as_float(u_.z & 0xffff0000u);                            \
        a6 += __uint_as_float(u_.w << 16);                                    \
        a7 += __uint_as_float(u_.w & 0xffff0000u);                            \
    }

    UNPACK(u0) UNPACK(u1) UNPACK(u2) UNPACK(u3) UNPACK(u4)
    UNPACK(u5) UNPACK(u6) UNPACK(u7) UNPACK(u8)

    // fold pass-1 into pass-2 scale domain: ws = 0.5*wr (exact pow2 scale)
    a0 *= 0.5f; a1 *= 0.5f; a2 *= 0.5f; a3 *= 0.5f;
    a4 *= 0.5f; a5 *= 0.5f; a6 *= 0.5f; a7 *= 0.5f;

    // ---- pass 2: 8-deep pipelined maskless walk (tails are SENT=zero) ----
    // Entry order e.x..f.w == s..s+7: summation order identical to R4/R5.
    // Prefetch max index: s=24 -> lists[lt][36..39], in-row (LROW=40).
    for (int s = 0; s < S8; s += 8) {
        const uint4 v0 = refk[(size_t)(e.x) * 8];
        const uint4 v1 = refk[(size_t)(e.y) * 8];
        const uint4 v2 = refk[(size_t)(e.z) * 8];
        const uint4 v3 = refk[(size_t)(e.w) * 8];
        const uint4 v4 = refk[(size_t)(f.x) * 8];
        const uint4 v5 = refk[(size_t)(f.y) * 8];
        const uint4 v6 = refk[(size_t)(f.z) * 8];
        const uint4 v7 = refk[(size_t)(f.w) * 8];
        const int4 en = *(const int4*)&lists[lt][s + 8];
        const int4 fn = *(const int4*)&lists[lt][s + 12];
        __builtin_amdgcn_sched_barrier(0);   // 8 loads in flight before use
        UNPACK(v0) UNPACK(v1) UNPACK(v2) UNPACK(v3)
        UNPACK(v4) UNPACK(v5) UNPACK(v6) UNPACK(v7)
        e = en; f = fn;
    }
#undef UNPACK

    // ---- epilogue: w = ws*nv + wr*Sreal (exact); out = a * wr / w ----
    const float wsum = ws * (float)nv + wr * (float)Sreal;   // nv>=1 always
    const float sc = wr / wsum;
    const int t = t0 + lt;
    size_t o = (size_t)(8 * k) * HW + t;
    out[o]                = a0 * sc;
    out[o + 1*(size_t)HW] = a1 * sc;
    out[o + 2*(size_t)HW] = a2 * sc;
    out[o + 3*(size_t)HW] = a3 * sc;
    out[o + 4*(size_t)HW] = a4 * sc;
    out[o + 5*(size_t)HW] = a5 * sc;
    out[o + 6*(size_t)HW] = a6 * sc;
    out[o + 7*(size_t)HW] = a7 * sc;
}

// ===========================================================================
// Fallback (tiny workspace): bins only, gather channel-major f32 ref with
// the SEL-chain walk.  Unchanged from baseline.
// ===========================================================================
__global__ __launch_bounds__(256) void fill_bins(
    const int2* __restrict__ nnf_rs, int* __restrict__ cnt,
    int* __restrict__ slots)
{
    int r = blockIdx.x * 256 + threadIdx.x;
    int2 s = nnf_rs[r];
    int bin = (s.x << 9) | s.y;
    int pos = atomicAdd(&cnt[bin], 1);
    if (pos < KCAP) slots[(bin << 4) + pos] = r;
}

__global__ __launch_bounds__(256) void gather8_f32(
    const float* __restrict__ reff,
    const int2*  __restrict__ nnf_sr,
    const int*   __restrict__ cnt,
    const int*   __restrict__ slots,
    float* __restrict__ out)
{
    const float ws = 1.0f / 262144.0f;
    const float wr = 2.0f / 262144.0f;

    const int tid = threadIdx.x;
    const int k   = tid & 7;
    const int t   = blockIdx.x * 32 + (tid >> 3);
    const int ty  = t >> 9, tx = t & 511;

    float a0=0,a1=0,a2=0,a3=0,a4=0,a5=0,a6=0,a7=0, w=0.f;

#define ACCUM(qv, mv)                                                         \
    {                                                                         \
        const int   q_ = (qv);                                                \
        const float m_ = (mv);                                                \
        const size_t c0_ = (size_t)(8 * k) * HW + q_;                         \
        a0 += reff[c0_ + 0*(size_t)HW] * m_;                                  \
        a1 += reff[c0_ + 1*(size_t)HW] * m_;                                  \
        a2 += reff[c0_ + 2*(size_t)HW] * m_;                                  \
        a3 += reff[c0_ + 3*(size_t)HW] * m_;                                  \
        a4 += reff[c0_ + 4*(size_t)HW] * m_;                                  \
        a5 += reff[c0_ + 5*(size_t)HW] * m_;                                  \
        a6 += reff[c0_ + 6*(size_t)HW] * m_;                                  \
        a7 += reff[c0_ + 7*(size_t)HW] * m_;                                  \
        w += m_;                                                              \
    }

    int mt0,mt1,mt2,mt3,mt4,mt5,mt6,mt7,mt8;
    int run = 0;

#define TAP(i, dy, dx)                                                        \
    {                                                                         \
        const int sy = ty - (dy), sx = tx - (dx);                             \
        const bool sval = ((unsigned)sy < 512u) & ((unsigned)sx < 512u);      \
        const int sidx = ((sy & 511) << 9) | (sx & 511);                      \
        mt##i = (sidx << 12) | ((i) << 8) | run;                              \
        const int c = cnt[sidx];                                              \
        run += sval ? min(c, KCAP) : 0;                                       \
        const int2 nn = nnf_sr[sidx];                                         \
        const int qy = nn.x + (dy), qx = nn.y + (dx);                         \
        const bool v = sval & ((unsigned)qy < 512u) & ((unsigned)qx < 512u);  \
        ACCUM((((qy & 511) << 9) | (qx & 511)), v ? ws : 0.f)                 \
    }

    TAP(0, -1, -1)  TAP(1, -1, 0)  TAP(2, -1, 1)
    TAP(3,  0, -1)  TAP(4,  0, 0)  TAP(5,  0, 1)
    TAP(6,  1, -1)  TAP(7,  1, 0)  TAP(8,  1, 1)
#undef TAP

    const int S = run;

#define SEL(i)  m_ = (s_ >= (mt##i & 255)) ? mt##i : m_;
#define ENTRY(sv)                                                             \
    {                                                                         \
        const int s_ = (sv);                                                  \
        int m_ = mt0;                                                         \
        SEL(1) SEL(2) SEL(3) SEL(4) SEL(5) SEL(6) SEL(7) SEL(8)               \
        const int off_ = m_ & 255;                                            \
        const int ii_  = (m_ >> 8) & 15;                                      \
        const int bs_  = (m_ >> 12) << 4;                                     \
        const int idx_ = min(s_ - off_, KCAP - 1);                            \
        const int e_   = slots[bs_ + idx_];                                   \
        const int ry_  = (e_ >> 9) & 511, rx_ = e_ & 511;                     \
        const int dyp_ = (ii_ * 11) >> 5;                                     \
        const int dy_  = dyp_ - 1, dx_ = ii_ - 3 * dyp_ - 1;                  \
        const int qy_  = ry_ + dy_, qx_ = rx_ + dx_;                          \
        const bool v_  = (s_ < S) &                                           \
                         ((unsigned)qy_ < 512u) & ((unsigned)qx_ < 512u);     \
        ACCUM((((qy_ & 511) << 9) | (qx_ & 511)), v_ ? wr : 0.f)              \
    }

    for (int s = 0; s < S; s += 2) {
        ENTRY(s)
        ENTRY(s + 1)
    }
#undef ENTRY
#undef SEL
#undef ACCUM

    if (w == 0.f) w = 1.f;
    const float inv = 1.f / w;
    size_t o = (size_t)(8 * k) * HW + t;
    out[o]                = a0 * inv;
    out[o + 1*(size_t)HW] = a1 * inv;
    out[o + 2*(size_t)HW] = a2 * inv;
    out[o + 3*(size_t)HW] = a3 * inv;
    out[o + 4*(size_t)HW] = a4 * inv;
    out[o + 5*(size_t)HW] = a5 * inv;
    out[o + 6*(size_t)HW] = a6 * inv;
    out[o + 7*(size_t)HW] = a7 * inv;
}

extern "C" void kernel_launch(void* const* d_in, const int* in_sizes, int n_in,
                              void* d_out, int out_size, void* d_ws, size_t ws_size,
                              hipStream_t stream)
{
    const float* ref    = (const float*)d_in[0];
    const int2*  nnf_sr = (const int2*)d_in[1];
    const int2*  nnf_rs = (const int2*)d_in[2];
    float* out = (float*)d_out;

    char* wsb = (char*)d_ws;
    const size_t refT_bytes = (size_t)HW * NC * 2 + 128;  // +128B sentinel rec
    const size_t cnt_bytes  = (size_t)HW * 4;             //  1 MiB
    const size_t slot_bytes = (size_t)HW * KCAP * 4;      // 16 MiB

    if (ws_size >= refT_bytes + cnt_bytes + slot_bytes) {   // ~49 MiB
        uint4* refu4 = (uint4*)wsb;
        int*   cntp  = (int*)(wsb + refT_bytes);
        int*   slots = (int*)(wsb + refT_bytes + cnt_bytes);

        hipMemsetAsync(cntp, 0, cnt_bytes, stream);
        prep_fill<<<4096 + HW / 256, 256, 0, stream>>>(
            (const float4*)ref, refu4, nnf_rs, cntp, slots);
        gather_lds<<<HW / 32, 256, 0, stream>>>(refu4, nnf_sr, cntp, slots, out);
    } else {
        // fallback: bins only, gather channel-major f32 ref directly
        int* cntp  = (int*)wsb;
        int* slots = cntp + HW;
        hipMemsetAsync(cntp, 0, cnt_bytes, stream);
        fill_bins<<<HW / 256, 256, 0, stream>>>(nnf_rs, cntp, slots);
        gather8_f32<<<HW / 32, 256, 0, stream>>>(ref, nnf_sr, cntp, slots, out);
    }
}